// Round 21
// baseline (86.940 us; speedup 1.0000x reference)
//
#include <hip/hip_runtime.h>
#include <hip/hip_bf16.h>

typedef __attribute__((ext_vector_type(4))) float f32x4;
typedef __attribute__((ext_vector_type(16))) float f32x16;
typedef __attribute__((ext_vector_type(8))) short bf16x8;

#define M_TOT 30752   // 8*62*62 output pixels

__device__ __forceinline__ unsigned short f2bf(float f) {
  unsigned int u = __float_as_uint(f);
  u = u + 0x7FFF + ((u >> 16) & 1);   // round-to-nearest-even
  return (unsigned short)(u >> 16);
}

__device__ __forceinline__ void gload16(const void* g, void* l) {
  __builtin_amdgcn_global_load_lds((const __attribute__((address_space(1))) unsigned int*)g,
                                   (__attribute__((address_space(3))) unsigned int*)l,
                                   16, 0, 0);
}

// ---- fused prep: blocks 0..575 = keff+k2t (hides under cast);
//                  blocks 576..4671 = cast x->bf16 (HBM-bound).  [R16, frozen]
__global__ __launch_bounds__(256) void fused_k(const float* __restrict__ x,
                                               const float* __restrict__ P,
                                               const float* __restrict__ Q,
                                               const float* __restrict__ S,
                                               unsigned short* __restrict__ xb,
                                               unsigned short* __restrict__ K2t) {
  __shared__ float ldsK[256 * 4];
  const int bid = blockIdx.x;
  const int t = threadIdx.x;

  if (bid >= 576) {                  // ---- cast x -> bf16 ----
    int i = (bid - 576) * 256 + t;
    const f32x4* xp = (const f32x4*)x;
    f32x4 a = xp[2 * i];
    f32x4 b = xp[2 * i + 1];
    bf16x8 o;
    o[0] = (short)f2bf(a[0]); o[1] = (short)f2bf(a[1]);
    o[2] = (short)f2bf(a[2]); o[3] = (short)f2bf(a[3]);
    o[4] = (short)f2bf(b[0]); o[5] = (short)f2bf(b[1]);
    o[6] = (short)f2bf(b[2]); o[7] = (short)f2bf(b[3]);
    ((bf16x8*)xb)[i] = o;
    return;
  }

  const int kk = bid / 64;           // 0..8
  const int f0 = (bid & 63) * 4;     // 0..252
  {                                  // phase 1: Keff slice -> LDS (thread = o)
    float k0 = 0.f, k1 = 0.f, k2 = 0.f, k3 = 0.f;
    const float* qp = Q + t * 144 + kk * 16;
    const float* sp = S + (t >> 4) * 4096 + (t & 15) * 256 + f0;
#pragma unroll
    for (int bi = 0; bi < 16; ++bi) {
      float qv = qp[bi];
      const float* s4 = sp + bi * 65536;
      k0 = fmaf(qv, s4[0], k0); k1 = fmaf(qv, s4[1], k1);
      k2 = fmaf(qv, s4[2], k2); k3 = fmaf(qv, s4[3], k3);
    }
    ldsK[t * 4 + 0] = k0; ldsK[t * 4 + 1] = k1;
    ldsK[t * 4 + 2] = k2; ldsK[t * 4 + 3] = k3;
  }
  __syncthreads();
  {                                  // phase 2: contraction over o (thread = ci)
    const int ci = t;
    float acc[4] = {0.f, 0.f, 0.f, 0.f};
#pragma unroll 8
    for (int o = 0; o < 256; ++o) {
      float pv = P[o * 256 + ci];
      acc[0] = fmaf(pv, ldsK[o * 4 + 0], acc[0]);
      acc[1] = fmaf(pv, ldsK[o * 4 + 1], acc[1]);
      acc[2] = fmaf(pv, ldsK[o * 4 + 2], acc[2]);
      acc[3] = fmaf(pv, ldsK[o * 4 + 3], acc[3]);
    }
#pragma unroll
    for (int j = 0; j < 4; ++j)
      K2t[kk * 65536 + (f0 + j) * 256 + ci] = f2bf(acc[j]);
  }
}

// ---- main: implicit-GEMM conv with 32x32x16 MFMA (peak shape: 2495 vs 2075
// TF, half the instruction count). Geometry = R20: 512 thr, 8 waves
// (sk x wm x wn), wave 64x64 over its K-half; BM=BN=128, BK=64; 2 blocks/CU
// (4 waves/SIMD). Wave = 2x2 32x32 frags; per step 8 b128 reads + 8 MFMA.
// Frag layout (m74/m101): A/B lane = row/col + 32*(k/8), 8 contig k-elems;
// slot = (kf*2+kq) ^ ((r32>>1)&3) -> distinct-mod-8 per 8 lanes (0-conflict
// under existing both-sides swizzle). C/D: col=lane&31, row=(reg&3)+8*(reg>>2)
// +4*kq. R17 one-barrier ring; grid 488 = 8 XCD x 61.
__global__ __launch_bounds__(512, 4) void conv_gemm(const unsigned short* __restrict__ xb,
                                                    const unsigned short* __restrict__ K2t,
                                                    float* __restrict__ out) {
  __shared__ __attribute__((aligned(16))) char smem[65536];  // 2 x (A16K + B16K)

  const int tid = threadIdx.x;
  const int lane = tid & 63;
  const int wid = tid >> 6;         // 0..7
  const int sk = wid >> 2;          // k-half
  const int wm = (wid >> 1) & 1;    // m-half
  const int wn = wid & 1;           // n-half

  const int wgid = (blockIdx.x & 7) * 61 + (blockIdx.x >> 3);
  if (wgid >= 482) return;
  const int mt = wgid >> 1;         // 0..240
  const int nt = wgid & 1;
  const int m0 = mt * 128;
  const int n0 = nt * 128;

  const int r32 = lane & 31;        // frag row/col
  const int kq = lane >> 5;         // k-quarter within K=16 (8 elems)
  const int swz = (r32 >> 1) & 3;   // read-side swizzle bits

  // staging identical to R20: thread t owns chunks {t, t+512} of A and B.
  const int s_src = ((tid & 3) ^ ((tid >> 3) & 3)) * 8;   // element offset
  int gA;
  {
    int m = m0 + (tid >> 2); if (m >= M_TOT) m = M_TOT - 1;
    int b = m / 3844; int rem = m - b * 3844;
    int h = rem / 62; int w = rem - h * 62;
    gA = ((b * 64 + h) * 64 + w) * 256 + s_src;
  }
  const int fB = (n0 + (tid >> 2)) * 256 + s_src;

  f32x16 acc[2][2];
#pragma unroll
  for (int i = 0; i < 2; ++i)
#pragma unroll
    for (int j = 0; j < 2; ++j)
#pragma unroll
      for (int e = 0; e < 16; ++e) acc[i][j][e] = 0.f;

  // read offsets: row stride 64B; mi/ni stride 32 rows = 2048B
  const int sl0 = ((0 + kq) ^ swz) << 4;   // kf=0 stored-slot byte offset
  const int sl1 = ((2 + kq) ^ swz) << 4;   // kf=1
  const int aBase = sk * 8192 + (wm * 64 + r32) * 64;           // A region
  const int bBase = 16384 + sk * 8192 + (wn * 64 + r32) * 64;   // B region

#define STAGE(t, base)                                                         \
  {                                                                            \
    int kk_ = (t) >> 2, cb_ = (t) & 3;                                         \
    int kh_ = kk_ / 3, kw_ = kk_ - kh_ * 3;                                    \
    int offA_ = kh_ * 16384 + kw_ * 256 + cb_ * 64;                            \
    int offB_ = kk_ * 65536 + cb_ * 64;                                        \
    unsigned short* bA = (unsigned short*)(base);                              \
    unsigned short* bB = (unsigned short*)((char*)(base) + 16384);             \
    gload16(xb + gA + offA_,       bA + tid * 8);                              \
    gload16(xb + gA + offA_ + 32,  bA + (tid + 512) * 8);                      \
    gload16(K2t + offB_ + fB,      bB + tid * 8);                              \
    gload16(K2t + offB_ + fB + 32, bB + (tid + 512) * 8);                      \
  }

  // prologue: stage tile 0, drain, sync
  STAGE(0, smem);
  asm volatile("s_waitcnt vmcnt(0)" ::: "memory");
  __builtin_amdgcn_sched_barrier(0);
  __builtin_amdgcn_s_barrier();
  __builtin_amdgcn_sched_barrier(0);

  for (int t = 0; t < 36; ++t) {
    char* cur = smem + (t & 1) * 32768;

    // 1) issue next tile's stage FIRST (hides under this step's compute)
    if (t < 35) STAGE(t + 1, smem + ((t + 1) & 1) * 32768);
    __builtin_amdgcn_sched_barrier(0);

    // 2) ds_read + MFMA (compiler emits counted lgkmcnt)
    bf16x8 a[2][2], b[2][2];   // [mi|ni][kf]
#pragma unroll
    for (int mi = 0; mi < 2; ++mi) {
      a[mi][0] = *(const bf16x8*)(cur + aBase + mi * 2048 + sl0);
      a[mi][1] = *(const bf16x8*)(cur + aBase + mi * 2048 + sl1);
    }
#pragma unroll
    for (int ni = 0; ni < 2; ++ni) {
      b[ni][0] = *(const bf16x8*)(cur + bBase + ni * 2048 + sl0);
      b[ni][1] = *(const bf16x8*)(cur + bBase + ni * 2048 + sl1);
    }
    __builtin_amdgcn_s_setprio(1);
#pragma unroll
    for (int kf = 0; kf < 2; ++kf)
#pragma unroll
      for (int mi = 0; mi < 2; ++mi)
#pragma unroll
        for (int ni = 0; ni < 2; ++ni)
          acc[mi][ni] = __builtin_amdgcn_mfma_f32_32x32x16_bf16(
              a[mi][kf], b[ni][kf], acc[mi][ni], 0, 0, 0);
    __builtin_amdgcn_s_setprio(0);

    // 3) wait AFTER compute; single barrier covers visibility + anti-overwrite
    if (t < 35) {
      __builtin_amdgcn_sched_barrier(0);
      asm volatile("s_waitcnt vmcnt(0)" ::: "memory");
      __builtin_amdgcn_sched_barrier(0);
      __builtin_amdgcn_s_barrier();
      __builtin_amdgcn_sched_barrier(0);
    }
  }

  __syncthreads();   // main loop done; smem reused as reduction buffer

  // epilogue: sk=1 waves stage acc (2x2x16 f32/lane) in LDS: 16 frags x 4KB
  // = 64KB. Layout frag*4096 + q*1024 + lane*16 (lane-contig, conflict-free).
  // D: row = m0 + wm*64 + mi*32 + q*8 + kq*4 + j;  col = n0 + wn*64 + ni*32 + r32.
  float* red = (float*)smem;
  if (sk == 1) {
#pragma unroll
    for (int mi = 0; mi < 2; ++mi)
#pragma unroll
      for (int ni = 0; ni < 2; ++ni) {
        const f32x4* av = (const f32x4*)&acc[mi][ni];
        int frag = ((wm * 2 + wn) * 2 + mi) * 2 + ni;
#pragma unroll
        for (int q = 0; q < 4; ++q)
          *(f32x4*)((char*)red + frag * 4096 + q * 1024 + lane * 16) = av[q];
      }
  }
  __syncthreads();
  if (sk == 0) {
#pragma unroll
    for (int mi = 0; mi < 2; ++mi) {
#pragma unroll
      for (int ni = 0; ni < 2; ++ni) {
        const f32x4* av = (const f32x4*)&acc[mi][ni];
        int frag = ((wm * 2 + wn) * 2 + mi) * 2 + ni;
        int f = n0 + wn * 64 + ni * 32 + r32;
#pragma unroll
        for (int q = 0; q < 4; ++q) {
          f32x4 o = *(const f32x4*)((char*)red + frag * 4096 + q * 1024 + lane * 16);
          o += av[q];
          int mb = m0 + wm * 64 + mi * 32 + q * 8 + kq * 4;
#pragma unroll
          for (int j = 0; j < 4; ++j) {
            int m = mb + j;
            if (m < M_TOT) out[m * 256 + f] = o[j];
          }
        }
      }
    }
  }
#undef STAGE
}

extern "C" void kernel_launch(void* const* d_in, const int* in_sizes, int n_in,
                              void* d_out, int out_size, void* d_ws, size_t ws_size,
                              hipStream_t stream) {
  const float* x = (const float*)d_in[0];   // [8,64,64,256]
  const float* P = (const float*)d_in[1];   // [256,256]
  const float* Q = (const float*)d_in[2];   // [256,3,3,16]
  const float* S = (const float*)d_in[3];   // [256,16,256]
  float* out = (float*)d_out;               // [8,62,62,256]

  char* ws = (char*)d_ws;
  unsigned short* xb  = (unsigned short*)ws;               // 16,777,216 B
  unsigned short* K2t = (unsigned short*)(ws + 16777216);  //  1,179,648 B

  fused_k<<<4672, 256, 0, stream>>>(x, P, Q, S, xb, K2t);
  conv_gemm<<<488, 512, 0, stream>>>(xb, K2t, out);
}

// Round 22
// 77.919 us; speedup vs baseline: 1.1158x; 1.1158x over previous
//
#include <hip/hip_runtime.h>
#include <hip/hip_bf16.h>

typedef __attribute__((ext_vector_type(4))) float f32x4;
typedef __attribute__((ext_vector_type(8))) short bf16x8;

#define M_TOT 30752   // 8*62*62 output pixels

__device__ __forceinline__ unsigned short f2bf(float f) {
  unsigned int u = __float_as_uint(f);
  u = u + 0x7FFF + ((u >> 16) & 1);   // round-to-nearest-even
  return (unsigned short)(u >> 16);
}

__device__ __forceinline__ void gload16(const void* g, void* l) {
  __builtin_amdgcn_global_load_lds((const __attribute__((address_space(1))) unsigned int*)g,
                                   (__attribute__((address_space(3))) unsigned int*)l,
                                   16, 0, 0);
}

// ---- fused prep: blocks 0..575 = keff+k2t (hides under cast);
//                  blocks 576..4671 = cast x->bf16 (HBM-bound).  [R16, frozen]
__global__ __launch_bounds__(256) void fused_k(const float* __restrict__ x,
                                               const float* __restrict__ P,
                                               const float* __restrict__ Q,
                                               const float* __restrict__ S,
                                               unsigned short* __restrict__ xb,
                                               unsigned short* __restrict__ K2t) {
  __shared__ float ldsK[256 * 4];
  const int bid = blockIdx.x;
  const int t = threadIdx.x;

  if (bid >= 576) {                  // ---- cast x -> bf16 ----
    int i = (bid - 576) * 256 + t;
    const f32x4* xp = (const f32x4*)x;
    f32x4 a = xp[2 * i];
    f32x4 b = xp[2 * i + 1];
    bf16x8 o;
    o[0] = (short)f2bf(a[0]); o[1] = (short)f2bf(a[1]);
    o[2] = (short)f2bf(a[2]); o[3] = (short)f2bf(a[3]);
    o[4] = (short)f2bf(b[0]); o[5] = (short)f2bf(b[1]);
    o[6] = (short)f2bf(b[2]); o[7] = (short)f2bf(b[3]);
    ((bf16x8*)xb)[i] = o;
    return;
  }

  const int kk = bid / 64;           // 0..8
  const int f0 = (bid & 63) * 4;     // 0..252
  {                                  // phase 1: Keff slice -> LDS (thread = o)
    float k0 = 0.f, k1 = 0.f, k2 = 0.f, k3 = 0.f;
    const float* qp = Q + t * 144 + kk * 16;
    const float* sp = S + (t >> 4) * 4096 + (t & 15) * 256 + f0;
#pragma unroll
    for (int bi = 0; bi < 16; ++bi) {
      float qv = qp[bi];
      const float* s4 = sp + bi * 65536;
      k0 = fmaf(qv, s4[0], k0); k1 = fmaf(qv, s4[1], k1);
      k2 = fmaf(qv, s4[2], k2); k3 = fmaf(qv, s4[3], k3);
    }
    ldsK[t * 4 + 0] = k0; ldsK[t * 4 + 1] = k1;
    ldsK[t * 4 + 2] = k2; ldsK[t * 4 + 3] = k3;
  }
  __syncthreads();
  {                                  // phase 2: contraction over o (thread = ci)
    const int ci = t;
    float acc[4] = {0.f, 0.f, 0.f, 0.f};
#pragma unroll 8
    for (int o = 0; o < 256; ++o) {
      float pv = P[o * 256 + ci];
      acc[0] = fmaf(pv, ldsK[o * 4 + 0], acc[0]);
      acc[1] = fmaf(pv, ldsK[o * 4 + 1], acc[1]);
      acc[2] = fmaf(pv, ldsK[o * 4 + 2], acc[2]);
      acc[3] = fmaf(pv, ldsK[o * 4 + 3], acc[3]);
    }
#pragma unroll
    for (int j = 0; j < 4; ++j)
      K2t[kk * 65536 + (f0 + j) * 256 + ci] = f2bf(acc[j]);
  }
}

// ---- main: implicit-GEMM conv, m201-style 4-PHASE fine interleave.
// M=30752, N=256 (full), K=2304. BM=128, BN=256, BK=64/step; 512 thr = 8
// waves (2m x 4n), wave 64x64, acc 4x4 frags. TRIPLE-buffer 3x48KB=144KB,
// depth-2 prefetch, counted vmcnt(6) at step head (never 0 till tail).
// Each step = 4 phases: {ds_read subtile (6 or 2) || 2 gloads of tile t+2 ->
// s_barrier -> lgkmcnt(0) -> setprio(1) 8-MFMA setprio(0) -> s_barrier}.
// R7's 128B-row XOR swizzle (measured 0 conflicts). 16x16x32 MFMA.
__global__ __launch_bounds__(512) void conv_gemm(const unsigned short* __restrict__ xb,
                                                 const unsigned short* __restrict__ K2t,
                                                 float* __restrict__ out) {
  __shared__ __attribute__((aligned(16))) char smem[147456];  // 3 x (A16K+B32K)

  const int tid = threadIdx.x;
  const int lane = tid & 63;
  const int wm = (tid >> 6) >> 2;   // 0..1
  const int wn = (tid >> 6) & 3;    // 0..3
  const int m0 = blockIdx.x * 128;

  // staging: thread t covers chunk (row t>>3, slot t&7) [+512-chunk repeats].
  // both-sides swizzle: source slot = (t&7) ^ ((t>>3)&7).
  const int swslot = ((tid & 7) ^ ((tid >> 3) & 7)) * 8;
  const int rA = tid >> 3;          // 0..63

  int gA0, gA1;
  {
    int m = m0 + rA; if (m >= M_TOT) m = M_TOT - 1;
    int b = m / 3844; int rem = m - b * 3844;
    int h = rem / 62; int w = rem - h * 62;
    gA0 = ((b * 64 + h) * 64 + w) * 256 + swslot;
    m = m0 + rA + 64; if (m >= M_TOT) m = M_TOT - 1;
    b = m / 3844; rem = m - b * 3844;
    h = rem / 62; w = rem - h * 62;
    gA1 = ((b * 64 + h) * 64 + w) * 256 + swslot;
  }
  int fB[4];
#pragma unroll
  for (int q = 0; q < 4; ++q) fB[q] = (rA + 64 * q) * 256 + swslot;

  f32x4 zero = {0.f, 0.f, 0.f, 0.f};
  f32x4 acc[4][4];
#pragma unroll
  for (int i = 0; i < 4; ++i)
#pragma unroll
    for (int j = 0; j < 4; ++j) acc[i][j] = zero;

  const int rl = lane & 15;
  const int kg = lane >> 4;
  const int xm = (lane & 7) << 4;   // read-side XOR ((row&7)<<4); row&7==rl&7

#define STAGE_A(t, base)                                                       \
  {                                                                            \
    int kk_ = (t) >> 2, cb_ = (t) & 3;                                         \
    int kh_ = kk_ / 3, kw_ = kk_ - kh_ * 3;                                    \
    int offA_ = kh_ * 16384 + kw_ * 256 + cb_ * 64;                            \
    unsigned short* bA = (unsigned short*)(base);                              \
    gload16(xb + gA0 + offA_, bA + tid * 8);                                   \
    gload16(xb + gA1 + offA_, bA + (tid + 512) * 8);                           \
  }
#define STAGE_B2(t, base, q0)                                                  \
  {                                                                            \
    int kk_ = (t) >> 2, cb_ = (t) & 3;                                         \
    int offB_ = kk_ * 65536 + cb_ * 64;                                        \
    unsigned short* bB = (unsigned short*)((char*)(base) + 16384);             \
    gload16(K2t + offB_ + fB[q0],     bB + (tid + 512 * (q0)) * 8);            \
    gload16(K2t + offB_ + fB[q0 + 1], bB + (tid + 512 * (q0 + 1)) * 8);        \
  }

#define AF(mi, ks, buf) \
  (*(const bf16x8*)((const char*)(buf) + (wm * 64 + (mi) * 16 + rl) * 128 + (((ks) * 64 + kg * 16) ^ xm)))
#define BF(ni, ks, buf) \
  (*(const bf16x8*)((const char*)(buf) + 16384 + (wn * 64 + (ni) * 16 + rl) * 128 + (((ks) * 64 + kg * 16) ^ xm)))

#define FENCE_MFMA8(M0, M1, b0, b1, b2, b3, a0_, a1_)                          \
  {                                                                            \
    __builtin_amdgcn_sched_barrier(0);                                         \
    __builtin_amdgcn_s_barrier();                                              \
    asm volatile("s_waitcnt lgkmcnt(0)" ::: "memory");                         \
    __builtin_amdgcn_sched_barrier(0);                                         \
    __builtin_amdgcn_s_setprio(1);                                             \
    acc[M0][0] = __builtin_amdgcn_mfma_f32_16x16x32_bf16(a0_, b0, acc[M0][0], 0, 0, 0); \
    acc[M0][1] = __builtin_amdgcn_mfma_f32_16x16x32_bf16(a0_, b1, acc[M0][1], 0, 0, 0); \
    acc[M0][2] = __builtin_amdgcn_mfma_f32_16x16x32_bf16(a0_, b2, acc[M0][2], 0, 0, 0); \
    acc[M0][3] = __builtin_amdgcn_mfma_f32_16x16x32_bf16(a0_, b3, acc[M0][3], 0, 0, 0); \
    acc[M1][0] = __builtin_amdgcn_mfma_f32_16x16x32_bf16(a1_, b0, acc[M1][0], 0, 0, 0); \
    acc[M1][1] = __builtin_amdgcn_mfma_f32_16x16x32_bf16(a1_, b1, acc[M1][1], 0, 0, 0); \
    acc[M1][2] = __builtin_amdgcn_mfma_f32_16x16x32_bf16(a1_, b2, acc[M1][2], 0, 0, 0); \
    acc[M1][3] = __builtin_amdgcn_mfma_f32_16x16x32_bf16(a1_, b3, acc[M1][3], 0, 0, 0); \
    __builtin_amdgcn_s_setprio(0);                                             \
    __builtin_amdgcn_sched_barrier(0);                                         \
    __builtin_amdgcn_s_barrier();                                              \
    __builtin_amdgcn_sched_barrier(0);                                         \
  }

  // step t: 4 phases; stage(t+2) spread 2A/2B/2B over phases 0-2
#define STEP(t, cur, nxt)                                                      \
  {                                                                            \
    if ((t) >= 34) asm volatile("s_waitcnt vmcnt(0)" ::: "memory");            \
    else           asm volatile("s_waitcnt vmcnt(6)" ::: "memory");            \
    __builtin_amdgcn_sched_barrier(0);                                         \
    __builtin_amdgcn_s_barrier();                                              \
    __builtin_amdgcn_sched_barrier(0);                                         \
    bf16x8 b0, b1, b2, b3, a0, a1;                                             \
    /* P0: 6 reads (ks0 full B + af0,af1), stage 2A(t+2), 8 MFMA */            \
    b0 = BF(0, 0, cur); b1 = BF(1, 0, cur); b2 = BF(2, 0, cur); b3 = BF(3, 0, cur); \
    a0 = AF(0, 0, cur); a1 = AF(1, 0, cur);                                    \
    if ((t) + 2 < 36) STAGE_A((t) + 2, nxt);                                   \
    FENCE_MFMA8(0, 1, b0, b1, b2, b3, a0, a1)                                  \
    /* P1: 2 reads (af2,af3 ks0), stage 2B, 8 MFMA */                          \
    a0 = AF(2, 0, cur); a1 = AF(3, 0, cur);                                    \
    if ((t) + 2 < 36) STAGE_B2((t) + 2, nxt, 0);                               \
    FENCE_MFMA8(2, 3, b0, b1, b2, b3, a0, a1)                                  \
    /* P2: 6 reads (ks1 full B + af0,af1), stage 2B, 8 MFMA */                 \
    b0 = BF(0, 1, cur); b1 = BF(1, 1, cur); b2 = BF(2, 1, cur); b3 = BF(3, 1, cur); \
    a0 = AF(0, 1, cur); a1 = AF(1, 1, cur);                                    \
    if ((t) + 2 < 36) STAGE_B2((t) + 2, nxt, 2);                               \
    FENCE_MFMA8(0, 1, b0, b1, b2, b3, a0, a1)                                  \
    /* P3: 2 reads (af2,af3 ks1), no stage, 8 MFMA */                          \
    a0 = AF(2, 1, cur); a1 = AF(3, 1, cur);                                    \
    FENCE_MFMA8(2, 3, b0, b1, b2, b3, a0, a1)                                  \
  }

  char* B0 = smem;
  char* B1 = smem + 49152;
  char* B2 = smem + 98304;

  STAGE_A(0, B0); STAGE_B2(0, B0, 0); STAGE_B2(0, B0, 2);
  STAGE_A(1, B1); STAGE_B2(1, B1, 0); STAGE_B2(1, B1, 2);

  for (int tt = 0; tt < 12; ++tt) {
    int t0 = tt * 3;
    STEP(t0,     B0, B2);
    STEP(t0 + 1, B1, B0);
    STEP(t0 + 2, B2, B1);
  }

  // epilogue: D row = kg*4 + r (+16*mi +64*wm), col = rl (+16*ni +64*wn)
#pragma unroll
  for (int mi = 0; mi < 4; ++mi) {
    int mb = m0 + wm * 64 + mi * 16 + kg * 4;
#pragma unroll
    for (int ni = 0; ni < 4; ++ni) {
      int f = wn * 64 + ni * 16 + rl;
#pragma unroll
      for (int r = 0; r < 4; ++r) {
        int m = mb + r;
        if (m < M_TOT) out[m * 256 + f] = acc[mi][ni][r];
      }
    }
  }
#undef STAGE_A
#undef STAGE_B2
#undef AF
#undef BF
#undef FENCE_MFMA8
#undef STEP
}

extern "C" void kernel_launch(void* const* d_in, const int* in_sizes, int n_in,
                              void* d_out, int out_size, void* d_ws, size_t ws_size,
                              hipStream_t stream) {
  const float* x = (const float*)d_in[0];   // [8,64,64,256]
  const float* P = (const float*)d_in[1];   // [256,256]
  const float* Q = (const float*)d_in[2];   // [256,3,3,16]
  const float* S = (const float*)d_in[3];   // [256,16,256]
  float* out = (float*)d_out;               // [8,62,62,256]

  char* ws = (char*)d_ws;
  unsigned short* xb  = (unsigned short*)ws;               // 16,777,216 B
  unsigned short* K2t = (unsigned short*)(ws + 16777216);  //  1,179,648 B

  fused_k<<<4672, 256, 0, stream>>>(x, P, Q, S, xb, K2t);
  conv_gemm<<<241, 512, 0, stream>>>(xb, K2t, out);
}